// Round 3
// baseline (142.424 us; speedup 1.0000x reference)
//
#include <hip/hip_runtime.h>
#include <hip/hip_bf16.h>

#define B_     4
#define V_IN   12500
#define V_OUT  50000
#define C_IN   64
#define C_OUT  32
#define SPIRAL 9
#define K_NNZ  3
#define ROWS   (B_ * V_OUT)       // 200000
#define KDIM   (SPIRAL * C_IN)    // 576
#define KSTEPS (KDIM / 16)        // 36 ksteps of K=16 (32x32x16 MFMA)
#define TILES  ((ROWS + 127) / 128)  // 1563 (last tile: 64 valid rows)
#define WFRAG_ELEMS (KSTEPS * 64 * 8)  // 18432 bf16 = 36864 B (whole W)

typedef __attribute__((ext_vector_type(8)))  short short8_t;   // 8 bf16 (4 VGPRs)
typedef __attribute__((ext_vector_type(16))) float floatx16;   // 32x32 acc

__device__ __forceinline__ unsigned short f32_to_bf16(float f) {
    unsigned int u = __float_as_uint(f);
    unsigned int r = u + 0x7fffu + ((u >> 16) & 1u);   // round-to-nearest-even
    return (unsigned short)(r >> 16);
}

// Kernel 1: up[b,v,c] = sum_k x[b, up_idx[v,k], c] * up_val[v,k]  -> bf16 in ws.
// Extra block: rearrange weight (576x32 fp32) into 32x32x16 A-fragment order
// (operand-swapped: A = W^T), bf16:
//   w_frag[(kstep*64 + lane)*8 + j] = W[kstep*16 + (lane>>5)*8 + j][lane&31]
__global__ __launch_bounds__(256) void upsample_kernel(
    const float* __restrict__ x,
    const int* __restrict__ up_idx,
    const float* __restrict__ up_val,
    const float* __restrict__ weight,
    unsigned short* __restrict__ up_bf16,
    unsigned short* __restrict__ w_frag)
{
    int tid = threadIdx.x;
    if (blockIdx.x == ROWS / 16) {
        for (int idx = tid; idx < WFRAG_ELEMS; idx += 256) {
            int j     = idx & 7;
            int lane  = (idx >> 3) & 63;
            int kstep = idx >> 9;
            int k = kstep * 16 + (lane >> 5) * 8 + j;
            int n = lane & 31;
            w_frag[idx] = f32_to_bf16(weight[k * C_OUT + n]);
        }
        return;
    }
    int r      = blockIdx.x * 16 + (tid >> 4);   // global row in [0, 200000)
    int lane16 = tid & 15;                       // 4 channels each
    int b = r / V_OUT;
    int v = r - b * V_OUT;
    const int*   ui = up_idx + v * K_NNZ;
    const float* uv = up_val + v * K_NNZ;
    float a0 = 0.f, a1 = 0.f, a2 = 0.f, a3 = 0.f;
#pragma unroll
    for (int k = 0; k < K_NNZ; k++) {
        int u = ui[k];
        float val = uv[k];
        const float4* xp = (const float4*)(x + ((size_t)b * V_IN + u) * C_IN) + lane16;
        float4 xv = *xp;
        a0 += val * xv.x; a1 += val * xv.y; a2 += val * xv.z; a3 += val * xv.w;
    }
    ushort4 o;
    o.x = f32_to_bf16(a0); o.y = f32_to_bf16(a1);
    o.z = f32_to_bf16(a2); o.w = f32_to_bf16(a3);
    *((ushort4*)(up_bf16 + (size_t)r * C_IN) + lane16) = o;
}

// Kernel 2: y[r, n] = relu( sum_f g[r,f] * W[f,n] + bias[n] ),
// g[r, s*64+c] = up[b, spiral[v,s], c].
// One 32x32x16 MFMA chain per wave: D = A(W^T) * B(g), 32 rows/wave,
// 128 rows/block (4 waves). D: col=lane&31 -> output row; row=(reg&3)+8*(reg>>2)
// +4*(lane>>5) -> output channel n. B: B[k=(lane>>5)*8+j][col=lane&31].
__global__ __launch_bounds__(256) void gemm_kernel(
    const unsigned short* __restrict__ up_bf16,
    const int* __restrict__ spiral,
    const unsigned short* __restrict__ w_frag,
    const float* __restrict__ bias,
    float* __restrict__ out)
{
    __shared__ __align__(16) unsigned short w_lds[WFRAG_ELEMS];  // 36864 B
    int tid  = threadIdx.x;
    int wave = tid >> 6;
    int lane = tid & 63;
    int c32  = lane & 31;    // D column = output row within wave tile
    int h    = lane >> 5;    // k-half selector

    int r = blockIdx.x * 128 + wave * 32 + c32;      // output row
    int valid = r < ROWS;
    int rs = valid ? r : ROWS - 1;                   // clamped for loads
    int b = rs / V_OUT;
    int v = rs - b * V_OUT;
    const int* sp = spiral + v * SPIRAL;
    size_t base = (size_t)b * V_OUT * C_IN;

    {   // stage whole W fragment array to LDS once per block (9 x 16B/thread)
        const uint4* src = (const uint4*)w_frag;
        uint4* dst = (uint4*)w_lds;
#pragma unroll
        for (int i = 0; i < WFRAG_ELEMS / 8 / 256; i++)
            dst[tid + i * 256] = src[tid + i * 256];
    }
    __syncthreads();

    // g-fragment loader: for spiral slot s, quarter q (kstep = s*4+q),
    // lane loads 8 bf16 at channel offset q*16 + h*8 of row spiral[v,s].
    floatx16 acc;
#pragma unroll
    for (int i = 0; i < 16; i++) acc[i] = 0.f;

    short8_t gbuf[2][4];
    {
        const unsigned short* rowp = up_bf16 + base + (size_t)sp[0] * C_IN + h * 8;
#pragma unroll
        for (int q = 0; q < 4; q++)
            gbuf[0][q] = *(const short8_t*)(rowp + q * 16);
    }
#pragma unroll
    for (int s = 0; s < SPIRAL; s++) {
        int cur = s & 1, nxt = cur ^ 1;
        if (s + 1 < SPIRAL) {
            const unsigned short* rowp = up_bf16 + base + (size_t)sp[s + 1] * C_IN + h * 8;
#pragma unroll
            for (int q = 0; q < 4; q++)
                gbuf[nxt][q] = *(const short8_t*)(rowp + q * 16);
        }
#pragma unroll
        for (int q = 0; q < 4; q++) {
            int kstep = s * 4 + q;
            const short8_t* wp = (const short8_t*)(w_lds + (kstep * 64 + lane) * 8);
            acc = __builtin_amdgcn_mfma_f32_32x32x16_bf16(*wp, gbuf[cur][q], acc, 0, 0, 0);
        }
    }

    // epilogue: lane holds 16 n's for row r: n = g*8 + h*4 + (reg&3), g=reg>>2
    if (valid) {
        float* op = out + (size_t)r * C_OUT;
#pragma unroll
        for (int g = 0; g < 4; g++) {
            float4 bv = *(const float4*)(bias + g * 8 + h * 4);
            float4 o4;
            o4.x = acc[g * 4 + 0] + bv.x;
            o4.y = acc[g * 4 + 1] + bv.y;
            o4.z = acc[g * 4 + 2] + bv.z;
            o4.w = acc[g * 4 + 3] + bv.w;
            o4.x = o4.x > 0.f ? o4.x : 0.f;
            o4.y = o4.y > 0.f ? o4.y : 0.f;
            o4.z = o4.z > 0.f ? o4.z : 0.f;
            o4.w = o4.w > 0.f ? o4.w : 0.f;
            *(float4*)(op + g * 8 + h * 4) = o4;
        }
    }
}

extern "C" void kernel_launch(void* const* d_in, const int* in_sizes, int n_in,
                              void* d_out, int out_size, void* d_ws, size_t ws_size,
                              hipStream_t stream) {
    const float* x      = (const float*)d_in[0];
    const int*   spiral = (const int*)d_in[1];
    const int*   up_idx = (const int*)d_in[2];
    const float* up_val = (const float*)d_in[3];
    const float* weight = (const float*)d_in[4];
    const float* bias   = (const float*)d_in[5];
    float* out = (float*)d_out;

    unsigned short* up_ws  = (unsigned short*)d_ws;          // 200000*64 bf16 = 25.6 MB
    unsigned short* w_frag = up_ws + (size_t)ROWS * C_IN;    // + 36864 B

    upsample_kernel<<<ROWS / 16 + 1, 256, 0, stream>>>(x, up_idx, up_val, weight, up_ws, w_frag);
    gemm_kernel<<<TILES, 256, 0, stream>>>(up_ws, spiral, w_frag, bias, out);
}

// Round 4
// 140.189 us; speedup vs baseline: 1.0159x; 1.0159x over previous
//
#include <hip/hip_runtime.h>
#include <hip/hip_bf16.h>

#define B_     4
#define V_IN   12500
#define V_OUT  50000
#define C_IN   64
#define C_OUT  32
#define SPIRAL 9
#define K_NNZ  3
#define ROWS   (B_ * V_OUT)       // 200000
#define GROUPS (ROWS / 16)        // 12500 16-row groups for k1
#define GRID1  2048               // k1 blocks (grid-stride) + 1 W-prep block
#define KDIM   (SPIRAL * C_IN)    // 576
#define KSTEPS (KDIM / 32)        // 18 (16x16x32 MFMA)
#define NTILES (ROWS / 64)        // 3125 64-row tiles for k2
#define GRID2  1024               // k2 blocks, grid-stride
#define WFRAG_ELEMS (KSTEPS * 2 * 64 * 8)  // 18432 bf16 = 36864 B

typedef __attribute__((ext_vector_type(8))) short short8_t;   // 8 bf16 (4 VGPRs)
typedef __attribute__((ext_vector_type(4))) float floatx4;    // 4 fp32 acc

__device__ __forceinline__ unsigned short f32_to_bf16(float f) {
    unsigned int u = __float_as_uint(f);
    unsigned int r = u + 0x7fffu + ((u >> 16) & 1u);   // round-to-nearest-even
    return (unsigned short)(r >> 16);
}

// Kernel 1: up[b,v,c] = sum_k x[b, up_idx[v,k], c] * up_val[v,k] -> bf16 in ws.
// Grid-stride over 12500 16-row groups (amortize launch ramp, keep loads deep).
// Block GRID1: rearrange weight (576x32 fp32) into MFMA fragment order (bf16),
// same layout validated in R1/R2:
//   w_frag[((kstep*2+ntile)*64+lane)*8+j] = W[kstep*32+(lane>>4)*8+j][ntile*16+(lane&15)]
__global__ __launch_bounds__(256) void upsample_kernel(
    const float* __restrict__ x,
    const int* __restrict__ up_idx,
    const float* __restrict__ up_val,
    const float* __restrict__ weight,
    unsigned short* __restrict__ up_bf16,
    unsigned short* __restrict__ w_frag)
{
    int tid = threadIdx.x;
    if (blockIdx.x == GRID1) {
        for (int idx = tid; idx < WFRAG_ELEMS; idx += 256) {
            int j     = idx & 7;
            int lane  = (idx >> 3) & 63;
            int ntile = (idx >> 9) & 1;
            int kstep = idx >> 10;
            int k = kstep * 32 + (lane >> 4) * 8 + j;
            int n = ntile * 16 + (lane & 15);
            w_frag[idx] = f32_to_bf16(weight[k * C_OUT + n]);
        }
        return;
    }
    int lane16 = tid & 15;                        // 4 channels each
    int sub    = tid >> 4;                        // row within group
    for (int grp = blockIdx.x; grp < GROUPS; grp += GRID1) {
        int r = grp * 16 + sub;                   // global row in [0, 200000)
        int b = r / V_OUT;
        int v = r - b * V_OUT;
        const int*   ui = up_idx + v * K_NNZ;
        const float* uv = up_val + v * K_NNZ;
        float a0 = 0.f, a1 = 0.f, a2 = 0.f, a3 = 0.f;
#pragma unroll
        for (int k = 0; k < K_NNZ; k++) {
            int u = ui[k];
            float val = uv[k];
            const float4* xp = (const float4*)(x + ((size_t)b * V_IN + u) * C_IN) + lane16;
            float4 xv = *xp;
            a0 += val * xv.x; a1 += val * xv.y; a2 += val * xv.z; a3 += val * xv.w;
        }
        ushort4 o;
        o.x = f32_to_bf16(a0); o.y = f32_to_bf16(a1);
        o.z = f32_to_bf16(a2); o.w = f32_to_bf16(a3);
        *((ushort4*)(up_bf16 + (size_t)r * C_IN) + lane16) = o;
    }
}

// Kernel 2: y[r,n] = relu( sum_f g[r,f] * W[f,n] + bias[n] ),
// g[r, s*64+c] = up[b, spiral[v,s], c].
// R1-validated fragment layout (16 rows/wave, 2x 16x16x32 MFMA chains, 18
// line-transactions per wave-load) + R2-validated swapped-operand epilogue
// (D = W^T * g => lane holds 8 consecutive n for one row => float4 stores).
// Grid-stride over 3125 tiles; W staged to LDS once per block.
__global__ __launch_bounds__(256) void gemm_kernel(
    const unsigned short* __restrict__ up_bf16,
    const int* __restrict__ spiral,
    const unsigned short* __restrict__ w_frag,
    const float* __restrict__ bias,
    float* __restrict__ out)
{
    __shared__ __align__(16) unsigned short w_lds[WFRAG_ELEMS];  // 36864 B
    int tid = threadIdx.x;
    {   // stage W fragments to LDS once per block
        const uint4* src = (const uint4*)w_frag;
        uint4* dst = (uint4*)w_lds;
#pragma unroll
        for (int i = 0; i < WFRAG_ELEMS / 8 / 256; i++)
            dst[tid + i * 256] = src[tid + i * 256];
    }
    __syncthreads();

    int wave = tid >> 6;
    int lane = tid & 63;
    int m    = lane & 15;
    int quad = lane >> 4;

    float4 bias0 = ((const float4*)bias)[quad];      // bias[quad*4 .. +3]
    float4 bias1 = ((const float4*)bias)[4 + quad];  // bias[16+quad*4 .. +3]

    for (int tile = blockIdx.x; tile < NTILES; tile += GRID2) {
        int r = tile * 64 + wave * 16 + m;           // this lane's output row
        int b = r / V_OUT;
        int v = r - b * V_OUT;
        const int* sp = spiral + v * SPIRAL;
        size_t base = (size_t)b * V_OUT * C_IN;

        // preload all 18 g-fragments (deep MLP: 18 x 16B in flight per lane;
        // g0/g1 of a row are the same 128B line -> L1 absorbs second touch)
        short8_t g0[SPIRAL], g1[SPIRAL];
#pragma unroll
        for (int s = 0; s < SPIRAL; s++) {
            const unsigned short* rowp = up_bf16 + base + (size_t)sp[s] * C_IN;
            g0[s] = *(const short8_t*)(rowp + quad * 8);
            g1[s] = *(const short8_t*)(rowp + 32 + quad * 8);
        }

        floatx4 acc0 = {0.f, 0.f, 0.f, 0.f};
        floatx4 acc1 = {0.f, 0.f, 0.f, 0.f};
#pragma unroll
        for (int kstep = 0; kstep < KSTEPS; kstep++) {
            short8_t gf = (kstep & 1) ? g1[kstep >> 1] : g0[kstep >> 1];
            const short8_t* wp0 = (const short8_t*)(w_lds + ((kstep * 2 + 0) * 64 + lane) * 8);
            const short8_t* wp1 = (const short8_t*)(w_lds + ((kstep * 2 + 1) * 64 + lane) * 8);
            acc0 = __builtin_amdgcn_mfma_f32_16x16x32_bf16(*wp0, gf, acc0, 0, 0, 0);
            acc1 = __builtin_amdgcn_mfma_f32_16x16x32_bf16(*wp1, gf, acc1, 0, 0, 0);
        }

        // epilogue: lane holds y[r][quad*4..+3] and y[r][16+quad*4..+3]
        float4 o0, o1;
        o0.x = acc0[0] + bias0.x; o0.y = acc0[1] + bias0.y;
        o0.z = acc0[2] + bias0.z; o0.w = acc0[3] + bias0.w;
        o1.x = acc1[0] + bias1.x; o1.y = acc1[1] + bias1.y;
        o1.z = acc1[2] + bias1.z; o1.w = acc1[3] + bias1.w;
        o0.x = o0.x > 0.f ? o0.x : 0.f;  o0.y = o0.y > 0.f ? o0.y : 0.f;
        o0.z = o0.z > 0.f ? o0.z : 0.f;  o0.w = o0.w > 0.f ? o0.w : 0.f;
        o1.x = o1.x > 0.f ? o1.x : 0.f;  o1.y = o1.y > 0.f ? o1.y : 0.f;
        o1.z = o1.z > 0.f ? o1.z : 0.f;  o1.w = o1.w > 0.f ? o1.w : 0.f;
        float* op = out + (size_t)r * C_OUT;
        *(float4*)(op + quad * 4)      = o0;
        *(float4*)(op + 16 + quad * 4) = o1;
    }
}

extern "C" void kernel_launch(void* const* d_in, const int* in_sizes, int n_in,
                              void* d_out, int out_size, void* d_ws, size_t ws_size,
                              hipStream_t stream) {
    const float* x      = (const float*)d_in[0];
    const int*   spiral = (const int*)d_in[1];
    const int*   up_idx = (const int*)d_in[2];
    const float* up_val = (const float*)d_in[3];
    const float* weight = (const float*)d_in[4];
    const float* bias   = (const float*)d_in[5];
    float* out = (float*)d_out;

    unsigned short* up_ws  = (unsigned short*)d_ws;          // 200000*64 bf16 = 25.6 MB
    unsigned short* w_frag = up_ws + (size_t)ROWS * C_IN;    // + 36864 B

    upsample_kernel<<<GRID1 + 1, 256, 0, stream>>>(x, up_idx, up_val, weight, up_ws, w_frag);
    gemm_kernel<<<GRID2, 256, 0, stream>>>(up_ws, spiral, w_frag, bias, out);
}

// Round 5
// 130.880 us; speedup vs baseline: 1.0882x; 1.0711x over previous
//
#include <hip/hip_runtime.h>
#include <hip/hip_bf16.h>

#define B_     4
#define V_IN   12500
#define V_OUT  50000
#define C_IN   64
#define C_OUT  32
#define SPIRAL 9
#define K_NNZ  3
#define ROWS   (B_ * V_OUT)       // 200000
#define KDIM   (SPIRAL * C_IN)    // 576
#define KSTEPS (KDIM / 32)        // 18 (16x16x32 MFMA)
#define WFRAG_ELEMS (KSTEPS * 2 * 64 * 8)  // 18432 bf16 = 36864 B

#define GROUPS_PER_B (V_OUT / 16) // 3125 16-row groups per batch (k1)
#define G1           2048         // k1 blocks (+1 W-prep); 256 per XCD
#define TILES_PER_B  782          // 781 full 64-row tiles + one 16-row tail (k2)
#define G2           1024         // k2 blocks; 128 per XCD

typedef __attribute__((ext_vector_type(8))) short short8_t;   // 8 bf16 (4 VGPRs)
typedef __attribute__((ext_vector_type(4))) float floatx4;    // 4 fp32 acc

__device__ __forceinline__ unsigned short f32_to_bf16(float f) {
    unsigned int u = __float_as_uint(f);
    unsigned int r = u + 0x7fffu + ((u >> 16) & 1u);   // round-to-nearest-even
    return (unsigned short)(r >> 16);
}

// Kernel 1: up[b,v,c] = sum_k x[b, up_idx[v,k], c] * up_val[v,k] -> bf16 in ws.
// XCD-swizzled: block i serves batch b = (i&7)>>1 only, so each XCD pair's L2
// caches x[b] (3.2 MB < 4 MB) and collects dirty up[b] lines for kernel 2.
// Block G1: rearrange weight (576x32 fp32) into MFMA fragment order (bf16):
//   w_frag[((kstep*2+ntile)*64+lane)*8+j] = W[kstep*32+(lane>>4)*8+j][ntile*16+(lane&15)]
__global__ __launch_bounds__(256) void upsample_kernel(
    const float* __restrict__ x,
    const int* __restrict__ up_idx,
    const float* __restrict__ up_val,
    const float* __restrict__ weight,
    unsigned short* __restrict__ up_bf16,
    unsigned short* __restrict__ w_frag)
{
    int tid = threadIdx.x;
    if (blockIdx.x == G1) {
        for (int idx = tid; idx < WFRAG_ELEMS; idx += 256) {
            int j     = idx & 7;
            int lane  = (idx >> 3) & 63;
            int ntile = (idx >> 9) & 1;
            int kstep = idx >> 10;
            int k = kstep * 32 + (lane >> 4) * 8 + j;
            int n = ntile * 16 + (lane & 15);
            w_frag[idx] = f32_to_bf16(weight[k * C_OUT + n]);
        }
        return;
    }
    int xcd = blockIdx.x & 7;
    int b   = xcd >> 1;                     // batch owned by this XCD pair
    int h   = xcd & 1;
    int j   = blockIdx.x >> 3;              // [0, 256)
    int lane16 = tid & 15;                  // 4 channels each
    int sub    = tid >> 4;                  // row within 16-row group

    const float* xb = x + (size_t)b * V_IN * C_IN;
    unsigned short* upb = up_bf16 + (size_t)b * V_OUT * C_IN;

    for (int gl = h + 2 * j; gl < GROUPS_PER_B; gl += 512) {
        int v = gl * 16 + sub;              // local row within batch b
        const int*   ui = up_idx + v * K_NNZ;
        const float* uv = up_val + v * K_NNZ;
        float a0 = 0.f, a1 = 0.f, a2 = 0.f, a3 = 0.f;
#pragma unroll
        for (int k = 0; k < K_NNZ; k++) {
            int u = ui[k];
            float val = uv[k];
            const float4* xp = (const float4*)(xb + (size_t)u * C_IN) + lane16;
            float4 xv = *xp;
            a0 += val * xv.x; a1 += val * xv.y; a2 += val * xv.z; a3 += val * xv.w;
        }
        ushort4 o;
        o.x = f32_to_bf16(a0); o.y = f32_to_bf16(a1);
        o.z = f32_to_bf16(a2); o.w = f32_to_bf16(a3);
        *((ushort4*)(upb + (size_t)v * C_IN) + lane16) = o;
    }
}

// Kernel 2: y[r,n] = relu( sum_f g[r,f] * W[f,n] + bias[n] ),
// g[r, s*64+c] = up[b, spiral[v,s], c].
// R1-validated fragment layout (16 rows/wave, 2x 16x16x32 MFMA chains) +
// swapped-operand epilogue (lane holds 8 consecutive n per row -> float4
// stores). XCD-swizzled with the SAME b map as kernel 1, so the gather hits
// up[b] (6.4 MB) mostly in the local XCD L2.
__global__ __launch_bounds__(256) void gemm_kernel(
    const unsigned short* __restrict__ up_bf16,
    const int* __restrict__ spiral,
    const unsigned short* __restrict__ w_frag,
    const float* __restrict__ bias,
    float* __restrict__ out)
{
    __shared__ __align__(16) unsigned short w_lds[WFRAG_ELEMS];  // 36864 B
    int tid = threadIdx.x;
    {   // stage W fragments to LDS once per block
        const uint4* src = (const uint4*)w_frag;
        uint4* dst = (uint4*)w_lds;
#pragma unroll
        for (int i = 0; i < WFRAG_ELEMS / 8 / 256; i++)
            dst[tid + i * 256] = src[tid + i * 256];
    }
    __syncthreads();

    int wave = tid >> 6;
    int lane = tid & 63;
    int m    = lane & 15;
    int quad = lane >> 4;

    int xcd = blockIdx.x & 7;
    int b   = xcd >> 1;
    int h   = xcd & 1;
    int j   = blockIdx.x >> 3;              // [0, 128)

    const unsigned short* upb = up_bf16 + (size_t)b * V_OUT * C_IN;
    float* outb = out + (size_t)b * V_OUT * C_OUT;

    float4 bias0 = ((const float4*)bias)[quad];      // bias[quad*4 .. +3]
    float4 bias1 = ((const float4*)bias)[4 + quad];  // bias[16+quad*4 .. +3]

    for (int tl = h + 2 * j; tl < TILES_PER_B; tl += 256) {
        int vr = tl * 64 + wave * 16 + m;            // local output row in b
        int valid = vr < V_OUT;                      // tail tile: 16 valid rows
        int v = valid ? vr : 0;
        const int* sp = spiral + v * SPIRAL;

        // preload all 18 g-fragments (18 x 16B in flight per lane)
        short8_t g0[SPIRAL], g1[SPIRAL];
#pragma unroll
        for (int s = 0; s < SPIRAL; s++) {
            const unsigned short* rowp = upb + (size_t)sp[s] * C_IN;
            g0[s] = *(const short8_t*)(rowp + quad * 8);
            g1[s] = *(const short8_t*)(rowp + 32 + quad * 8);
        }

        floatx4 acc0 = {0.f, 0.f, 0.f, 0.f};
        floatx4 acc1 = {0.f, 0.f, 0.f, 0.f};
#pragma unroll
        for (int kstep = 0; kstep < KSTEPS; kstep++) {
            short8_t gf = (kstep & 1) ? g1[kstep >> 1] : g0[kstep >> 1];
            const short8_t* wp0 = (const short8_t*)(w_lds + ((kstep * 2 + 0) * 64 + lane) * 8);
            const short8_t* wp1 = (const short8_t*)(w_lds + ((kstep * 2 + 1) * 64 + lane) * 8);
            acc0 = __builtin_amdgcn_mfma_f32_16x16x32_bf16(*wp0, gf, acc0, 0, 0, 0);
            acc1 = __builtin_amdgcn_mfma_f32_16x16x32_bf16(*wp1, gf, acc1, 0, 0, 0);
        }

        if (valid) {
            float4 o0, o1;
            o0.x = acc0[0] + bias0.x; o0.y = acc0[1] + bias0.y;
            o0.z = acc0[2] + bias0.z; o0.w = acc0[3] + bias0.w;
            o1.x = acc1[0] + bias1.x; o1.y = acc1[1] + bias1.y;
            o1.z = acc1[2] + bias1.z; o1.w = acc1[3] + bias1.w;
            o0.x = o0.x > 0.f ? o0.x : 0.f;  o0.y = o0.y > 0.f ? o0.y : 0.f;
            o0.z = o0.z > 0.f ? o0.z : 0.f;  o0.w = o0.w > 0.f ? o0.w : 0.f;
            o1.x = o1.x > 0.f ? o1.x : 0.f;  o1.y = o1.y > 0.f ? o1.y : 0.f;
            o1.z = o1.z > 0.f ? o1.z : 0.f;  o1.w = o1.w > 0.f ? o1.w : 0.f;
            float* op = outb + (size_t)vr * C_OUT;
            *(float4*)(op + quad * 4)      = o0;
            *(float4*)(op + 16 + quad * 4) = o1;
        }
    }
}

extern "C" void kernel_launch(void* const* d_in, const int* in_sizes, int n_in,
                              void* d_out, int out_size, void* d_ws, size_t ws_size,
                              hipStream_t stream) {
    const float* x      = (const float*)d_in[0];
    const int*   spiral = (const int*)d_in[1];
    const int*   up_idx = (const int*)d_in[2];
    const float* up_val = (const float*)d_in[3];
    const float* weight = (const float*)d_in[4];
    const float* bias   = (const float*)d_in[5];
    float* out = (float*)d_out;

    unsigned short* up_ws  = (unsigned short*)d_ws;          // 200000*64 bf16 = 25.6 MB
    unsigned short* w_frag = up_ws + (size_t)ROWS * C_IN;    // + 36864 B

    upsample_kernel<<<G1 + 1, 256, 0, stream>>>(x, up_idx, up_val, weight, up_ws, w_frag);
    gemm_kernel<<<G2, 256, 0, stream>>>(up_ws, spiral, w_frag, bias, out);
}

// Round 6
// 129.817 us; speedup vs baseline: 1.0971x; 1.0082x over previous
//
#include <hip/hip_runtime.h>
#include <hip/hip_bf16.h>

#define B_     4
#define V_IN   12500
#define V_OUT  50000
#define C_IN   64
#define C_OUT  32
#define SPIRAL 9
#define K_NNZ  3
#define ROWS   (B_ * V_OUT)       // 200000
#define KDIM   (SPIRAL * C_IN)    // 576
#define KSTEPS (KDIM / 32)        // 18 (16x16x32 MFMA)
#define WFRAG_ELEMS (KSTEPS * 2 * 64 * 8)  // 18432 bf16 = 36864 B

#define GROUPS_PER_B (V_OUT / 16) // 3125 16-row groups per batch (k1)
#define G1           2048         // k1 blocks (+1 W-prep); 256 per XCD
#define TILES_PER_B  782          // 781 full 64-row tiles + one 16-row tail (k2)
#define G2           512          // k2 blocks; 64 per XCD; 2 blocks/CU at ~244 VGPR

typedef __attribute__((ext_vector_type(8))) short short8_t;   // 8 bf16 (4 VGPRs)
typedef __attribute__((ext_vector_type(4))) float floatx4;    // 4 fp32 acc

__device__ __forceinline__ unsigned short f32_to_bf16(float f) {
    unsigned int u = __float_as_uint(f);
    unsigned int r = u + 0x7fffu + ((u >> 16) & 1u);   // round-to-nearest-even
    return (unsigned short)(r >> 16);
}

// Kernel 1 (unchanged from R5): up[b,v,c] = sum_k x[b,up_idx[v,k],c]*up_val[v,k]
// -> bf16 in ws. XCD-swizzled: block i serves batch b=(i&7)>>1 so each XCD
// pair's L2 caches x[b] (3.2 MB < 4 MB) and holds dirty up[b] lines for k2.
// Block G1: rearrange weight (576x32 fp32) into MFMA fragment order (bf16):
//   w_frag[((kstep*2+ntile)*64+lane)*8+j] = W[kstep*32+(lane>>4)*8+j][ntile*16+(lane&15)]
__global__ __launch_bounds__(256) void upsample_kernel(
    const float* __restrict__ x,
    const int* __restrict__ up_idx,
    const float* __restrict__ up_val,
    const float* __restrict__ weight,
    unsigned short* __restrict__ up_bf16,
    unsigned short* __restrict__ w_frag)
{
    int tid = threadIdx.x;
    if (blockIdx.x == G1) {
        for (int idx = tid; idx < WFRAG_ELEMS; idx += 256) {
            int j     = idx & 7;
            int lane  = (idx >> 3) & 63;
            int ntile = (idx >> 9) & 1;
            int kstep = idx >> 10;
            int k = kstep * 32 + (lane >> 4) * 8 + j;
            int n = ntile * 16 + (lane & 15);
            w_frag[idx] = f32_to_bf16(weight[k * C_OUT + n]);
        }
        return;
    }
    int xcd = blockIdx.x & 7;
    int b   = xcd >> 1;                     // batch owned by this XCD pair
    int h   = xcd & 1;
    int j   = blockIdx.x >> 3;              // [0, 256)
    int lane16 = tid & 15;                  // 4 channels each
    int sub    = tid >> 4;                  // row within 16-row group

    const float* xb = x + (size_t)b * V_IN * C_IN;
    unsigned short* upb = up_bf16 + (size_t)b * V_OUT * C_IN;

    for (int gl = h + 2 * j; gl < GROUPS_PER_B; gl += 512) {
        int v = gl * 16 + sub;              // local row within batch b
        const int*   ui = up_idx + v * K_NNZ;
        const float* uv = up_val + v * K_NNZ;
        float a0 = 0.f, a1 = 0.f, a2 = 0.f, a3 = 0.f;
#pragma unroll
        for (int k = 0; k < K_NNZ; k++) {
            int u = ui[k];
            float val = uv[k];
            const float4* xp = (const float4*)(xb + (size_t)u * C_IN) + lane16;
            float4 xv = *xp;
            a0 += val * xv.x; a1 += val * xv.y; a2 += val * xv.z; a3 += val * xv.w;
        }
        ushort4 o;
        o.x = f32_to_bf16(a0); o.y = f32_to_bf16(a1);
        o.z = f32_to_bf16(a2); o.w = f32_to_bf16(a3);
        *((ushort4*)(upb + (size_t)v * C_IN) + lane16) = o;
    }
}

// Kernel 2: y[r,n] = relu( sum_f g[r,f]*W[f,n] + bias[n] ),
// g[r, s*64+c] = up[b, spiral[v,s], c].
// R1-validated fragment layout + swapped-operand epilogue. NEW in R6: the
// entire W (36 fragments x 16 B = 144 VGPRs) is register-resident, loaded
// once per block from w_frag; NO LDS and NO barriers in the kernel. Inner
// loop is gather loads + MFMA only. 2 blocks/CU at ~244 VGPR.
__global__ __launch_bounds__(256, 2) void gemm_kernel(
    const unsigned short* __restrict__ up_bf16,
    const int* __restrict__ spiral,
    const unsigned short* __restrict__ w_frag,
    const float* __restrict__ bias,
    float* __restrict__ out)
{
    int tid  = threadIdx.x;
    int wave = tid >> 6;
    int lane = tid & 63;
    int m    = lane & 15;
    int quad = lane >> 4;

    // W fragments -> registers, once per block. 36 coalesced 16-B loads/lane.
    short8_t w[2 * KSTEPS];
#pragma unroll
    for (int f = 0; f < 2 * KSTEPS; f++)
        w[f] = *(const short8_t*)(w_frag + ((size_t)f * 64 + lane) * 8);

    int xcd = blockIdx.x & 7;
    int b   = xcd >> 1;
    int h   = xcd & 1;
    int j   = blockIdx.x >> 3;              // [0, 64)

    const unsigned short* upb = up_bf16 + (size_t)b * V_OUT * C_IN;
    float* outb = out + (size_t)b * V_OUT * C_OUT;

    float4 bias0 = ((const float4*)bias)[quad];      // bias[quad*4 .. +3]
    float4 bias1 = ((const float4*)bias)[4 + quad];  // bias[16+quad*4 .. +3]

    for (int tl = h + 2 * j; tl < TILES_PER_B; tl += 128) {
        int vr = tl * 64 + wave * 16 + m;            // local output row in b
        int valid = vr < V_OUT;                      // tail tile: 16 valid rows
        int v = valid ? vr : 0;
        const int* sp = spiral + v * SPIRAL;

        // preload all 18 g-fragments (18 x 16B in flight per lane)
        short8_t g0[SPIRAL], g1[SPIRAL];
#pragma unroll
        for (int s = 0; s < SPIRAL; s++) {
            const unsigned short* rowp = upb + (size_t)sp[s] * C_IN;
            g0[s] = *(const short8_t*)(rowp + quad * 8);
            g1[s] = *(const short8_t*)(rowp + 32 + quad * 8);
        }

        floatx4 acc0 = {0.f, 0.f, 0.f, 0.f};
        floatx4 acc1 = {0.f, 0.f, 0.f, 0.f};
#pragma unroll
        for (int kstep = 0; kstep < KSTEPS; kstep++) {
            short8_t gf = (kstep & 1) ? g1[kstep >> 1] : g0[kstep >> 1];
            acc0 = __builtin_amdgcn_mfma_f32_16x16x32_bf16(w[kstep * 2 + 0], gf, acc0, 0, 0, 0);
            acc1 = __builtin_amdgcn_mfma_f32_16x16x32_bf16(w[kstep * 2 + 1], gf, acc1, 0, 0, 0);
        }

        if (valid) {
            float4 o0, o1;
            o0.x = acc0[0] + bias0.x; o0.y = acc0[1] + bias0.y;
            o0.z = acc0[2] + bias0.z; o0.w = acc0[3] + bias0.w;
            o1.x = acc1[0] + bias1.x; o1.y = acc1[1] + bias1.y;
            o1.z = acc1[2] + bias1.z; o1.w = acc1[3] + bias1.w;
            o0.x = o0.x > 0.f ? o0.x : 0.f;  o0.y = o0.y > 0.f ? o0.y : 0.f;
            o0.z = o0.z > 0.f ? o0.z : 0.f;  o0.w = o0.w > 0.f ? o0.w : 0.f;
            o1.x = o1.x > 0.f ? o1.x : 0.f;  o1.y = o1.y > 0.f ? o1.y : 0.f;
            o1.z = o1.z > 0.f ? o1.z : 0.f;  o1.w = o1.w > 0.f ? o1.w : 0.f;
            float* op = outb + (size_t)vr * C_OUT;
            *(float4*)(op + quad * 4)      = o0;
            *(float4*)(op + 16 + quad * 4) = o1;
        }
    }
}

extern "C" void kernel_launch(void* const* d_in, const int* in_sizes, int n_in,
                              void* d_out, int out_size, void* d_ws, size_t ws_size,
                              hipStream_t stream) {
    const float* x      = (const float*)d_in[0];
    const int*   spiral = (const int*)d_in[1];
    const int*   up_idx = (const int*)d_in[2];
    const float* up_val = (const float*)d_in[3];
    const float* weight = (const float*)d_in[4];
    const float* bias   = (const float*)d_in[5];
    float* out = (float*)d_out;

    unsigned short* up_ws  = (unsigned short*)d_ws;          // 200000*64 bf16 = 25.6 MB
    unsigned short* w_frag = up_ws + (size_t)ROWS * C_IN;    // + 36864 B

    upsample_kernel<<<G1 + 1, 256, 0, stream>>>(x, up_idx, up_val, weight, up_ws, w_frag);
    gemm_kernel<<<G2, 256, 0, stream>>>(up_ws, spiral, w_frag, bias, out);
}